// Round 9
// baseline (42369.617 us; speedup 1.0000x reference)
//
#include <hip/hip_runtime.h>
#include <hip/hip_bf16.h>

#define BATCH 64
#define SEQ   2048
#define DIN   64
#define HID   256
#define NCLS  8

__device__ __forceinline__ float sigm(float x)  { return 1.0f / (1.0f + __expf(-x)); }
__device__ __forceinline__ float tanh_f(float x){ return 1.0f - 2.0f / (__expf(2.0f * x) + 1.0f); }

// Tag-in-value: low 6 mantissa bits carry step tag (<=63 ulp ~ 3.8e-6 rel).
// Readiness travels inside the data word -> no fences, no flags, ever.
__device__ __forceinline__ float tagf(float v, unsigned tag) {
    return __uint_as_float((__float_as_uint(v) & ~63u) | tag);
}
__device__ __forceinline__ int tagok(float v, unsigned tag) {
    return (__float_as_uint(v) & 63u) == tag;
}
// slow channel: agent scope (uncached, fabric-coherent, 64B-amplified - AVOID on hot path)
__device__ __forceinline__ float aload(float* p) {
    return __hip_atomic_load(p, __ATOMIC_RELAXED, __HIP_MEMORY_SCOPE_AGENT);
}
__device__ __forceinline__ void astore(float* p, float v) {
    __hip_atomic_store(p, v, __ATOMIC_RELAXED, __HIP_MEMORY_SCOPE_AGENT);
}
// fast channel: plain coalesced L2-cached access (compiler-uncacheable via atomic qual)
__device__ __forceinline__ float wload(float* p) {
    return __hip_atomic_load(p, __ATOMIC_RELAXED, __HIP_MEMORY_SCOPE_WORKGROUP);
}
__device__ __forceinline__ void wstore(float* p, float v) {
    __hip_atomic_store(p, v, __ATOMIC_RELAXED, __HIP_MEMORY_SCOPE_WORKGROUP);
}

// Dual-path ring read: try fast (same-XCD L2) with bounded retry, fall back to
// the guaranteed agent channel. Sticky slowmode skips futile fast tries when
// placement is cross-XCD. Wave-coherent (__all over the full wave).
__device__ __forceinline__ float ring_read(float* fsrc, float* ssrc,
                                           unsigned want, bool& slowmode) {
    float hv = 0.f; bool ok = false;
    const int fastmax = slowmode ? 2 : 40;
    for (int it = 0; it < fastmax; ++it) {
        if (!ok) { float tmp = wload(fsrc); if (tagok(tmp, want)) { hv = tmp; ok = true; } }
        if (__all(ok)) { slowmode = false; return hv; }
        if (it >= 3) __builtin_amdgcn_s_sleep(1);
    }
    slowmode = true;
    for (;;) {
        if (!ok) { float tmp = aload(ssrc); if (tagok(tmp, want)) { hv = tmp; ok = true; } }
        if (__all(ok)) return hv;
        __builtin_amdgcn_s_sleep(2);
    }
}

// out[b][t][c] = bfc[c]; FC overwrites t < len, so t >= len keeps exactly bfc.
__global__ void init_out_kernel(float* __restrict__ out, const float* __restrict__ bfc) {
    int idx = blockIdx.x * blockDim.x + threadIdx.x;
    if (idx < BATCH * SEQ * NCLS) out[idx] = bfc[idx & 7];
}

// ---------------------------------------------------------------------------
// L0: 256 blocks = mem(8) x pair(32); block serves batches {2P,2P+1}.
// Members of a pair have blockIdx stride 32 (== 0 mod 8 -> same XCD under the
// empirical round-robin mapping; correctness does NOT depend on it thanks to
// the agent fallback channel). Weights 40 f32/thread, register-resident.
// ---------------------------------------------------------------------------
__global__ __launch_bounds__(1024) void lstm_l0_kernel(
    const float* __restrict__ x,    const float* __restrict__ Wih0,
    const float* __restrict__ Whh0, const float* __restrict__ bih0,
    const float* __restrict__ bhh0, float* __restrict__ hist,
    float* __restrict__ ringF, float* __restrict__ ringS, int smask)
{
    const int P   = blockIdx.x & 31;
    const int mem = blockIdx.x >> 5;       // 0..7
    const int tid = threadIdx.x;
    const int p   = tid >> 7;              // 0..7 col-chunk (40 wide), wave-uniform
    const int r   = tid & 127;
    const int row = (r >> 5) * 256 + mem * 32 + (r & 31);

    float w[40];
#pragma unroll
    for (int q = 0; q < 40; ++q) {
        int col = p * 40 + q;
        w[q] = (col < DIN) ? Wih0[row * DIN + col] : Whh0[row * HID + (col - DIN)];
    }
#pragma unroll
    for (int q = 0; q < 40; ++q) asm volatile("" : "+v"(w[q]));

    const int isRed = (tid < 64);
    const int isLd  = (tid >= 64 && tid < 512);         // 448 loaders
    const int isXw  = (tid >= 544 && tid < 576);        // 32 x float4 writers

    float bias4[4] = {0.f, 0.f, 0.f, 0.f};
    if (isRed) {
        int k = tid & 31;
#pragma unroll
        for (int g4 = 0; g4 < 4; ++g4) {
            int rg = g4 * 256 + mem * 32 + k;
            bias4[g4] = bih0[rg] + bhh0[rg];
        }
    }
    float creg = 0.f;
    bool  slowmode = false;

    int ln = 0, lj = 0;
    if (isLd) {
        int i = tid - 64;
        ln = (i >= 224);
        int jj = i - (ln ? 224 : 0);
        lj = jj + (jj >= mem * 32 ? 32 : 0);            // skip own 32-slice
    }
    int xn = 0, xc = 0;
    float4 xreg = make_float4(0.f, 0.f, 0.f, 0.f);
    if (isXw) { xn = (tid - 544) >> 4; xc = ((tid - 544) & 15) * 4; }

    __shared__ __align__(16) float v[640];    // [n][ x(64) | h1prev(256) ]
    __shared__ float pb[2048];                // [n][p][r]

    if (isRed) v[(tid >> 5) * 320 + 64 + mem * 32 + (tid & 31)] = 0.f;
    if (isLd)  v[ln * 320 + 64 + lj] = 0.f;
    if (isXw)  *(float4*)&v[xn * 320 + xc] =
        *(const float4*)&x[((size_t)(2 * P + xn) * SEQ) * DIN + xc];
    __syncthreads();

    for (int t = 0; t < SEQ; ++t) {
        float a0 = 0.f, a1 = 0.f;
#pragma unroll
        for (int qq = 0; qq < 10; ++qq) {
            float4 va = *(const float4*)&v[p * 40 + qq * 4];        // uniform bcast
            a0 = fmaf(w[qq * 4 + 0], va.x, a0); a0 = fmaf(w[qq * 4 + 1], va.y, a0);
            a0 = fmaf(w[qq * 4 + 2], va.z, a0); a0 = fmaf(w[qq * 4 + 3], va.w, a0);
            float4 vb2 = *(const float4*)&v[320 + p * 40 + qq * 4];
            a1 = fmaf(w[qq * 4 + 0], vb2.x, a1); a1 = fmaf(w[qq * 4 + 1], vb2.y, a1);
            a1 = fmaf(w[qq * 4 + 2], vb2.z, a1); a1 = fmaf(w[qq * 4 + 3], vb2.w, a1);
        }
        if (isXw && t + 1 < SEQ)
            xreg = *(const float4*)&x[((size_t)(2 * P + xn) * SEQ + (t + 1)) * DIN + xc];
        pb[tid]        = a0;
        pb[1024 + tid] = a1;
        __syncthreads();                               // B1

        const int slot = t & smask;
        const unsigned want = (unsigned)((t + 1) & 63);
        if (isRed) {
            int n = tid >> 5, k = tid & 31, b = 2 * P + n;
            float s0 = bias4[0], s1 = bias4[1], s2 = bias4[2], s3 = bias4[3];
#pragma unroll
            for (int q8 = 0; q8 < 8; ++q8) {
                int base = n * 1024 + q8 * 128 + k;
                s0 += pb[base];       s1 += pb[base + 32];
                s2 += pb[base + 64];  s3 += pb[base + 96];
            }
            float iv = sigm(s0), fv = sigm(s1), gv = tanh_f(s2), ov = sigm(s3);
            creg = fv * creg + iv * gv;
            float h = ov * tanh_f(creg);
            hist[((size_t)t * BATCH + b) * HID + mem * 32 + k] = h;   // plain, for L1
            if (t + 1 < SEQ) {
                v[n * 320 + 64 + mem * 32 + k] = h;                   // own slice
                size_t off = ((size_t)slot * BATCH + b) * HID + mem * 32 + k;
                float tv = tagf(h, want);
                wstore(&ringF[off], tv);   // fast: shared-L2 channel
                astore(&ringS[off], tv);   // slow: fabric-coherent channel
            }
        } else if (isLd) {
            if (t + 1 < SEQ) {
                size_t off = ((size_t)slot * BATCH + (2 * P + ln)) * HID + lj;
                v[ln * 320 + 64 + lj] = ring_read(&ringF[off], &ringS[off], want, slowmode);
            }
        } else if (isXw) {
            if (t + 1 < SEQ) *(float4*)&v[xn * 320 + xc] = xreg;
        }
        __syncthreads();                               // B2
    }
}

// ---------------------------------------------------------------------------
// L1 + FC: 256 blocks = mem(16) x group(16); block serves batches 4g..4g+3.
// Member stride 16 (== 0 mod 8). h1[t] plain-loaded from hist (L0 kernel
// completed -> caches flushed at kernel boundary), prefetched one step ahead.
// h2 exchange via the same dual-channel tagged rings.
// ---------------------------------------------------------------------------
__global__ __launch_bounds__(1024) void lstm_l1_kernel(
    const float* __restrict__ hist, const float* __restrict__ Wih1,
    const float* __restrict__ Whh1, const float* __restrict__ bih1,
    const float* __restrict__ bhh1, const float* __restrict__ Wfc,
    const float* __restrict__ bfc,  const int* __restrict__ lengths,
    float* __restrict__ out, float* __restrict__ ringF, float* __restrict__ ringS,
    int smask)
{
    const int g   = blockIdx.x & 15;
    const int mem = blockIdx.x >> 4;       // 0..15
    const int tid = threadIdx.x;
    const int p   = tid >> 6;              // 0..15 col-chunk (32 wide), wave-uniform
    const int r   = tid & 63;
    const int row = (r >> 4) * 256 + mem * 16 + (r & 15);

    float w[32];
#pragma unroll
    for (int q = 0; q < 32; ++q) {
        int col = p * 32 + q;
        w[q] = (col < HID) ? Wih1[row * HID + col] : Whh1[row * HID + (col - HID)];
    }
#pragma unroll
    for (int q = 0; q < 32; ++q) asm volatile("" : "+v"(w[q]));

    float bias4[4] = {0.f, 0.f, 0.f, 0.f};
    if (tid < 64) {
        int k = tid & 15;
#pragma unroll
        for (int g4 = 0; g4 < 4; ++g4) {
            int rg = g4 * 256 + mem * 16 + k;
            bias4[g4] = bih1[rg] + bhh1[rg];
        }
    }
    float creg = 0.f;
    bool  slowmode = false;

    const int nf = mem & 3;                // FC batch within group
    const int c0 = (mem >> 2) * 2;         // FC class base
    float wfc = 0.f;
    if (tid < 512) wfc = Wfc[(c0 + (tid >> 8)) * HID + (tid & 255)];
    asm volatile("" : "+v"(wfc));
    const int   lenb = lengths[4 * g + nf];
    const float bfc0 = bfc[c0], bfc1 = bfc[c0 + 1];

    int ln = 0, lj = 0;
    if (tid >= 64) {
        int i = tid - 64;
        ln = i / 240;
        int jj = i - ln * 240;
        lj = jj + (jj >= mem * 16 ? 16 : 0);            // skip own 16-slice
    }
    const int isHw = (tid >= 544 && tid < 800);
    int hn = 0, hc = 0;
    float4 hreg = make_float4(0.f, 0.f, 0.f, 0.f);
    if (isHw) { hn = (tid - 544) >> 6; hc = ((tid - 544) & 63) * 4; }

    __shared__ __align__(16) float vb[2048];  // [n][ h1(256) | h2prev(256) ]
    __shared__ float pb[4128];                // [n] stride 1032 (pad +8)
    __shared__ float fcred[8];

    if (isHw) *(float4*)&vb[hn * 512 + hc] =
        *(const float4*)&hist[((size_t)0 * BATCH + 4 * g + hn) * HID + hc];
    if (tid < 64) vb[(tid >> 4) * 512 + 256 + mem * 16 + (tid & 15)] = 0.f;
    if (tid >= 64) vb[ln * 512 + 256 + lj] = 0.f;
    __syncthreads();

    for (int t = 0; t < SEQ; ++t) {
        float a0 = 0.f, a1 = 0.f, a2 = 0.f, a3 = 0.f;
#pragma unroll
        for (int qq = 0; qq < 8; ++qq) {
            int base = p * 32 + qq * 4;
            float4 v0 = *(const float4*)&vb[base];
            a0 = fmaf(w[qq * 4 + 0], v0.x, a0); a0 = fmaf(w[qq * 4 + 1], v0.y, a0);
            a0 = fmaf(w[qq * 4 + 2], v0.z, a0); a0 = fmaf(w[qq * 4 + 3], v0.w, a0);
            float4 v1 = *(const float4*)&vb[512 + base];
            a1 = fmaf(w[qq * 4 + 0], v1.x, a1); a1 = fmaf(w[qq * 4 + 1], v1.y, a1);
            a1 = fmaf(w[qq * 4 + 2], v1.z, a1); a1 = fmaf(w[qq * 4 + 3], v1.w, a1);
            float4 v2 = *(const float4*)&vb[1024 + base];
            a2 = fmaf(w[qq * 4 + 0], v2.x, a2); a2 = fmaf(w[qq * 4 + 1], v2.y, a2);
            a2 = fmaf(w[qq * 4 + 2], v2.z, a2); a2 = fmaf(w[qq * 4 + 3], v2.w, a2);
            float4 v3 = *(const float4*)&vb[1536 + base];
            a3 = fmaf(w[qq * 4 + 0], v3.x, a3); a3 = fmaf(w[qq * 4 + 1], v3.y, a3);
            a3 = fmaf(w[qq * 4 + 2], v3.z, a3); a3 = fmaf(w[qq * 4 + 3], v3.w, a3);
        }
        if (isHw && t + 1 < SEQ)                       // prefetch h1[t+1]
            hreg = *(const float4*)&hist[((size_t)(t + 1) * BATCH + 4 * g + hn) * HID + hc];
        pb[p * 64 + r]        = a0;
        pb[1032 + p * 64 + r] = a1;
        pb[2064 + p * 64 + r] = a2;
        pb[3096 + p * 64 + r] = a3;
        // FC partial for step t-1 (vb h2-half holds h2[t-1])
        float fval = 0.f;
        if (t > 0 && tid < 512) {
            fval = vb[nf * 512 + 256 + (tid & 255)] * wfc;
            fval += __shfl_xor(fval, 1);
            fval += __shfl_xor(fval, 2);
            fval += __shfl_xor(fval, 4);
            fval += __shfl_xor(fval, 8);
            fval += __shfl_xor(fval, 16);
            fval += __shfl_xor(fval, 32);
            if ((tid & 63) == 0) fcred[tid >> 6] = fval;
        }
        __syncthreads();                               // B1

        const int slot = t & smask;
        const unsigned want = (unsigned)((t + 1) & 63);
        if (tid < 64) {
            int n = tid >> 4, k = tid & 15, b = 4 * g + n;
            float s0 = bias4[0], s1 = bias4[1], s2 = bias4[2], s3 = bias4[3];
#pragma unroll
            for (int q16 = 0; q16 < 16; ++q16) {
                int base = n * 1032 + q16 * 64 + k;
                s0 += pb[base];       s1 += pb[base + 16];
                s2 += pb[base + 32];  s3 += pb[base + 48];
            }
            float iv = sigm(s0), fv = sigm(s1), gv = tanh_f(s2), ov = sigm(s3);
            creg = fv * creg + iv * gv;
            float h = ov * tanh_f(creg);
            vb[n * 512 + 256 + mem * 16 + k] = h;      // own slice
            size_t off = ((size_t)slot * BATCH + b) * HID + mem * 16 + k;
            float tv = tagf(h, want);
            wstore(&ringF[off], tv);
            astore(&ringS[off], tv);
        } else {
            if ((tid == 64 || tid == 65) && t > 0 && (t - 1) < lenb) {
                int cls = tid - 64;
                float s2 = fcred[cls * 4 + 0] + fcred[cls * 4 + 1]
                         + fcred[cls * 4 + 2] + fcred[cls * 4 + 3];
                out[((size_t)(4 * g + nf) * SEQ + (t - 1)) * NCLS + c0 + cls]
                    = (cls ? bfc1 : bfc0) + s2;
            }
            if (isHw && t + 1 < SEQ) *(float4*)&vb[hn * 512 + hc] = hreg;
            size_t off = ((size_t)slot * BATCH + (4 * g + ln)) * HID + lj;
            vb[ln * 512 + 256 + lj] = ring_read(&ringF[off], &ringS[off], want, slowmode);
        }
        __syncthreads();                               // B2
    }

    // epilogue: FC for t = SEQ-1 (vb h2-half now holds h2[SEQ-1])
    float fval = 0.f;
    if (tid < 512) {
        fval = vb[nf * 512 + 256 + (tid & 255)] * wfc;
        fval += __shfl_xor(fval, 1);
        fval += __shfl_xor(fval, 2);
        fval += __shfl_xor(fval, 4);
        fval += __shfl_xor(fval, 8);
        fval += __shfl_xor(fval, 16);
        fval += __shfl_xor(fval, 32);
        if ((tid & 63) == 0) fcred[tid >> 6] = fval;
    }
    __syncthreads();
    if (tid < 2 && (SEQ - 1) < lenb) {
        float s2 = fcred[tid * 4 + 0] + fcred[tid * 4 + 1]
                 + fcred[tid * 4 + 2] + fcred[tid * 4 + 3];
        out[((size_t)(4 * g + nf) * SEQ + (SEQ - 1)) * NCLS + c0 + tid]
            = (tid ? bfc1 : bfc0) + s2;
    }
}

// ---------------------------------------------------------------------------
extern "C" void kernel_launch(void* const* d_in, const int* in_sizes, int n_in,
                              void* d_out, int out_size, void* d_ws, size_t ws_size,
                              hipStream_t stream) {
    (void)in_sizes; (void)n_in; (void)out_size;
    const float* x     = (const float*)d_in[0];
    const int*   lens  = (const int*)  d_in[1];
    const float* Wih0  = (const float*)d_in[2];
    const float* Whh0  = (const float*)d_in[3];
    const float* bih0  = (const float*)d_in[4];
    const float* bhh0  = (const float*)d_in[5];
    const float* Wih1  = (const float*)d_in[6];
    const float* Whh1  = (const float*)d_in[7];
    const float* bih1  = (const float*)d_in[8];
    const float* bhh1  = (const float*)d_in[9];
    const float* Wfc   = (const float*)d_in[10];
    const float* bfc   = (const float*)d_in[11];
    float* out = (float*)d_out;
    char*  ws  = (char*)d_ws;

    const size_t histsz = (size_t)SEQ * BATCH * HID * 4;     // 128 MiB
    const size_t slotsz = (size_t)BATCH * HID * 4;           // 64 KiB
    int depth = 16;                                          // ring slots
    while (depth >= 2 && 4 * (size_t)depth * slotsz + histsz > ws_size) depth >>= 1;
    if (depth < 2) return;
    const size_t R = (size_t)depth * slotsz;

    float* ringF0 = (float*)(ws);
    float* ringS0 = (float*)(ws + R);
    float* ringF1 = (float*)(ws + 2 * R);
    float* ringS1 = (float*)(ws + 3 * R);
    float* hist   = (float*)(ws + 4 * R);

    // rings must be zero so no stale/poison dword can alias a valid tag
    // (tag 0 is never 'want' at t=0: want=(t+1)&63 = 1)
    hipMemsetAsync(ws, 0, 4 * R, stream);
    init_out_kernel<<<(BATCH * SEQ * NCLS + 255) / 256, 256, 0, stream>>>(out, bfc);
    lstm_l0_kernel<<<256, 1024, 0, stream>>>(x, Wih0, Whh0, bih0, bhh0, hist,
                                             ringF0, ringS0, depth - 1);
    lstm_l1_kernel<<<256, 1024, 0, stream>>>(hist, Wih1, Whh1, bih1, bhh1, Wfc, bfc,
                                             lens, out, ringF1, ringS1, depth - 1);
}